// Round 9
// baseline (703.421 us; speedup 1.0000x reference)
//
#include <hip/hip_runtime.h>
#include <hip/hip_cooperative_groups.h>

namespace cg = cooperative_groups;

#define SL  2048
#define BSZ 32
#define DIM 1024
#define NH  16
#define HD  64

typedef __attribute__((ext_vector_type(4))) float f32x4;
typedef __attribute__((ext_vector_type(8))) short s16x8;

static __device__ __forceinline__ short f2bf(float f) {
    union { float f; unsigned u; } v; v.f = f;
    unsigned r = (v.u + 0x7fffu + ((v.u >> 16) & 1u)) >> 16;  // RNE
    return (short)r;
}

union SharedU {
    struct { float red[256]; float sq[HD]; } p1;
    union {
        short ulds[NH * 1024];                       // 32 KB, XOR-swizzled chunks
        struct { float mred[4][16]; float lred[4][16]; } r;  // time-aliased after MFMA
    } p2;
    struct { float wlds[128 * 16]; float Tl[16];
             float mred8[8][16]; float lred8[8][16];
             f32x4 redW[4][16][16]; f32x4 redV[4][16]; } p3;   // 26.7 KB
    struct { float red[4][64]; } p45;
};
// sizeof(SharedU) == 32768 exactly -> 5 blocks/CU by LDS; launch_bounds(256,4)
// caps VGPR at 128 -> 4 blocks/CU by VGPR; cooperative max >= 1024 blocks.

// ---------- phase 1: u[b][h][j] = 0.125 * sum_i (query[b].Wq[h*64+i]) * Wk[h*64+i][j]
static __device__ __forceinline__ void phase_u(int blk, int t, SharedU* sh,
                                               const float* __restrict__ query,
                                               const float* __restrict__ Wq,
                                               const float* __restrict__ Wk,
                                               short* __restrict__ u) {
    int b = blk & 31;
    int h = blk >> 5;
    {
        int i  = t >> 2;
        int kq = t & 3;
        const float* q = query + (size_t)b * DIM + kq * 256;
        const float* w = Wq + (size_t)(h * HD + i) * DIM + kq * 256;
        f32x4 acc = {0.f, 0.f, 0.f, 0.f};
#pragma unroll 4
        for (int k = 0; k < 256; k += 4)
            acc += *(const f32x4*)(q + k) * *(const f32x4*)(w + k);
        sh->p1.red[t] = acc[0] + acc[1] + acc[2] + acc[3];
    }
    __syncthreads();
    if (t < HD)
        sh->p1.sq[t] = (sh->p1.red[t*4] + sh->p1.red[t*4+1] +
                        sh->p1.red[t*4+2] + sh->p1.red[t*4+3]) * 0.125f;
    __syncthreads();
    f32x4 acc = {0.f, 0.f, 0.f, 0.f};
    const float* wk = Wk + (size_t)(h * HD) * DIM;
#pragma unroll 8
    for (int i = 0; i < HD; ++i) {
        float s = sh->p1.sq[i];
        const float* row = wk + (size_t)i * DIM;
        acc[0] += s * row[t];
        acc[1] += s * row[t + 256];
        acc[2] += s * row[t + 512];
        acc[3] += s * row[t + 768];
    }
    short* ub = u + ((size_t)(b * NH + h)) * DIM;
    ub[t]       = f2bf(acc[0]);
    ub[t + 256] = f2bf(acc[1]);
    ub[t + 512] = f2bf(acc[2]);
    ub[t + 768] = f2bf(acc[3]);
}

// ---------- phase 2: dot[b][s][h] + per-block LSE partials (1024 blocks: 32 b x 32 st)
static __device__ __forceinline__ void phase_dot(int blk, int t, SharedU* sh,
                                                 const float* __restrict__ keys,
                                                 const short* __restrict__ u,
                                                 float* __restrict__ dotb,
                                                 float2* __restrict__ part) {
    int b  = blk & 31;
    int st = blk >> 5;
    int s0 = st * 64;
    short* ulds = sh->p2.ulds;
    {   // stage u with 16B-chunk XOR swizzle: chunk c of row -> c ^ (row&7)
        const uint4* src = (const uint4*)(u + (size_t)b * NH * DIM);
        for (int idx = t; idx < NH * DIM / 8; idx += 256) {
            int row = idx >> 7;
            int c   = idx & 127;
            *(uint4*)&ulds[row * 1024 + ((c ^ (row & 7)) << 3)] = src[idx];
        }
    }
    __syncthreads();
    int lane = t & 63;
    int wave = t >> 6;
    int lrow = lane & 15;
    int kgrp = lane >> 4;
    int swz  = (lrow & 7) << 3;      // in shorts; kj is 8-short aligned
    f32x4 acc = {0.f, 0.f, 0.f, 0.f};
    const float* ka = keys + ((size_t)(s0 + wave * 16 + lrow) * BSZ + b) * DIM;
#pragma unroll 4
    for (int k0 = 0; k0 < DIM; k0 += 32) {
        int kj = k0 + kgrp * 8;
        s16x8 bf = *(const s16x8*)&ulds[lrow * 1024 + (kj ^ swz)];
        f32x4 a0 = *(const f32x4*)(ka + kj);
        f32x4 a1 = *(const f32x4*)(ka + kj + 4);
        s16x8 af;
        af[0]=f2bf(a0[0]); af[1]=f2bf(a0[1]); af[2]=f2bf(a0[2]); af[3]=f2bf(a0[3]);
        af[4]=f2bf(a1[0]); af[5]=f2bf(a1[1]); af[6]=f2bf(a1[2]); af[7]=f2bf(a1[3]);
        acc = __builtin_amdgcn_mfma_f32_16x16x32_bf16(af, bf, acc, 0, 0, 0);
    }
    size_t obase = ((size_t)b * SL + (s0 + wave * 16 + kgrp * 4)) * NH + lrow;
#pragma unroll
    for (int r = 0; r < 4; ++r)
        dotb[obase + (size_t)r * NH] = acc[r];

    __syncthreads();   // all ulds reads done -> safe to alias with r.mred/r.lred
    float m = fmaxf(fmaxf(acc[0], acc[1]), fmaxf(acc[2], acc[3]));
    m = fmaxf(m, __shfl_xor(m, 16));
    m = fmaxf(m, __shfl_xor(m, 32));
    if (lane < 16) sh->p2.r.mred[wave][lrow] = m;
    __syncthreads();
    float mb = fmaxf(fmaxf(sh->p2.r.mred[0][lrow], sh->p2.r.mred[1][lrow]),
                     fmaxf(sh->p2.r.mred[2][lrow], sh->p2.r.mred[3][lrow]));
    float lsum = __expf(acc[0]-mb) + __expf(acc[1]-mb) + __expf(acc[2]-mb) + __expf(acc[3]-mb);
    lsum += __shfl_xor(lsum, 16);
    lsum += __shfl_xor(lsum, 32);
    if (lane < 16) sh->p2.r.lred[wave][lrow] = lsum;
    __syncthreads();
    if (t < 16) {
        float mbb = fmaxf(fmaxf(sh->p2.r.mred[0][t], sh->p2.r.mred[1][t]),
                          fmaxf(sh->p2.r.mred[2][t], sh->p2.r.mred[3][t]));
        float lb  = sh->p2.r.lred[0][t] + sh->p2.r.lred[1][t]
                  + sh->p2.r.lred[2][t] + sh->p2.r.lred[3][t];
        part[((size_t)b * 32 + st) * 16 + t] = make_float2(mbb, lb);
    }
}

// ---------- phase 3: z halves (1024 blocks: 32 b x 16 jc x 2 sh)
static __device__ __forceinline__ void phase_z(int blk, int t, SharedU* sh,
                                               const float* __restrict__ values,
                                               const float* __restrict__ dotb,
                                               const float2* __restrict__ part,
                                               float* __restrict__ z) {
    int b   = blk & 31;
    int jc  = (blk >> 5) & 15;
    int shf = blk >> 9;
    int ssub = t >> 4;
    int jq = t & 15;
    int j = jc * 64 + jq * 4;
    int wv = __builtin_amdgcn_readfirstlane(t >> 6);
    int lane = t & 63;

    if (t < 128) {
        int h = t & 15, g = t >> 4;
        const float2* pb = part + (size_t)b * 32 * 16 + h;
        float2 p0 = pb[(g*4+0)*16], p1 = pb[(g*4+1)*16],
               p2 = pb[(g*4+2)*16], p3v = pb[(g*4+3)*16];
        float M = fmaxf(fmaxf(p0.x, p1.x), fmaxf(p2.x, p3v.x));
        float L = p0.y*__expf(p0.x-M) + p1.y*__expf(p1.x-M)
                + p2.y*__expf(p2.x-M) + p3v.y*__expf(p3v.x-M);
        sh->p3.mred8[g][h] = M; sh->p3.lred8[g][h] = L;
    }
    __syncthreads();
    if (t < 16) {
        float M = sh->p3.mred8[0][t];
#pragma unroll
        for (int g = 1; g < 8; ++g) M = fmaxf(M, sh->p3.mred8[g][t]);
        float L = 0.f;
#pragma unroll
        for (int g = 0; g < 8; ++g) L += sh->p3.lred8[g][t] * __expf(sh->p3.mred8[g][t] - M);
        sh->p3.Tl[t] = M + __logf(L);
    }

    f32x4 acc[NH];
#pragma unroll
    for (int h = 0; h < NH; ++h) acc[h] = (f32x4){0.f,0.f,0.f,0.f};
    f32x4 accV = {0.f,0.f,0.f,0.f};

    const float* vbase = values + (size_t)b * DIM + j;
    const float* wbase = dotb + ((size_t)b * SL + shf * 1024) * NH;

    for (int ph = 0; ph < 8; ++ph) {
        __syncthreads();
        {
            const f32x4* src = (const f32x4*)(wbase + ph * 128 * NH);
            f32x4* dst = (f32x4*)sh->p3.wlds;
            dst[t]       = src[t];
            dst[t + 256] = src[t + 256];
        }
        __syncthreads();
        int sbase = shf * 1024 + ph * 128;
#pragma unroll 4
        for (int it = 0; it < 8; ++it) {
            int s_loc = it * 16 + ssub;
            f32x4 v = *(const f32x4*)(vbase + (size_t)(sbase + s_loc) * (BSZ * DIM));
            const float* wr = sh->p3.wlds + s_loc * 16;
#pragma unroll
            for (int h = 0; h < NH; ++h) {
                float wh = wr[h];
                acc[h] += v * wh;
            }
            accV += v;
        }
    }

#pragma unroll
    for (int h = 0; h < NH; ++h) {
#pragma unroll
        for (int e = 0; e < 4; ++e) {
            float x0 = acc[h][e];
            x0 += __shfl_xor(x0, 16);
            x0 += __shfl_xor(x0, 32);
            acc[h][e] = x0;
        }
    }
#pragma unroll
    for (int e = 0; e < 4; ++e) {
        float x0 = accV[e];
        x0 += __shfl_xor(x0, 16);
        x0 += __shfl_xor(x0, 32);
        accV[e] = x0;
    }
    if (lane < 16) {
#pragma unroll
        for (int h = 0; h < NH; ++h) sh->p3.redW[wv][h][lane] = acc[h];
        sh->p3.redV[wv][lane] = accV;
    }
    __syncthreads();
    int h2 = t >> 4, q = t & 15;
    f32x4 sumW = sh->p3.redW[0][h2][q] + sh->p3.redW[1][h2][q]
               + sh->p3.redW[2][h2][q] + sh->p3.redW[3][h2][q];
    f32x4 sumV = sh->p3.redV[0][q] + sh->p3.redV[1][q]
               + sh->p3.redV[2][q] + sh->p3.redV[3][q];
    float Th = sh->p3.Tl[h2];
    f32x4 zv = sumW - Th * sumV;
    float* zp = z + (size_t)shf * (BSZ * NH * DIM);
    *(f32x4*)(zp + ((size_t)(b * NH + h2)) * DIM + jc * 64 + q * 4) = zv;
}

// ---------- phase 4: attn = (z0+z1) @ Wv^T  (512 blocks: 16 oc x 32 b)
static __device__ __forceinline__ void phase_attn(int blk, int t, SharedU* sh,
                                                  const float* __restrict__ z,
                                                  const float* __restrict__ Wv,
                                                  float* __restrict__ attn) {
    int oc = blk & 15;
    int b  = blk >> 4;
    int wv = __builtin_amdgcn_readfirstlane(t >> 6);
    int lane = t & 63;
    int o = oc * 64 + lane;
    int row = b * 16 + oc;
    const float* arow  = z + (size_t)row * DIM + wv * 256;
    const float* a2row = z + (size_t)(BSZ * NH * DIM) + (size_t)row * DIM + wv * 256;
    const float* wrow  = Wv + (size_t)o * DIM + wv * 256;
    f32x4 acc = {0.f, 0.f, 0.f, 0.f};
#pragma unroll 4
    for (int k = 0; k < 256; k += 4) {
        f32x4 a = *(const f32x4*)(arow + k) + *(const f32x4*)(a2row + k);
        acc += a * *(const f32x4*)(wrow + k);
    }
    sh->p45.red[wv][lane] = acc[0] + acc[1] + acc[2] + acc[3];
    __syncthreads();
    if (t < 64)
        attn[(size_t)b * DIM + oc * 64 + t] =
            sh->p45.red[0][t] + sh->p45.red[1][t] + sh->p45.red[2][t] + sh->p45.red[3][t];
}

// ---------- phase 5: out = attn @ Wo^T  (512 blocks)
static __device__ __forceinline__ void phase_out(int blk, int t, SharedU* sh,
                                                 const float* __restrict__ attn,
                                                 const float* __restrict__ Wo,
                                                 float* __restrict__ out) {
    int oc = blk & 15;
    int b  = blk >> 4;
    int wv = __builtin_amdgcn_readfirstlane(t >> 6);
    int lane = t & 63;
    int o = oc * 64 + lane;
    const float* arow = attn + (size_t)b * DIM + wv * 256;
    const float* wrow = Wo + (size_t)o * DIM + wv * 256;
    f32x4 acc = {0.f, 0.f, 0.f, 0.f};
#pragma unroll 4
    for (int k = 0; k < 256; k += 4)
        acc += *(const f32x4*)(arow + k) * *(const f32x4*)(wrow + k);
    sh->p45.red[wv][lane] = acc[0] + acc[1] + acc[2] + acc[3];
    __syncthreads();
    if (t < 64)
        out[(size_t)b * DIM + oc * 64 + t] =
            sh->p45.red[0][t] + sh->p45.red[1][t] + sh->p45.red[2][t] + sh->p45.red[3][t];
}

// ================= fused cooperative kernel =================
__global__ __launch_bounds__(256, 4) void k_mega(
    const float* __restrict__ query, const float* __restrict__ keys,
    const float* __restrict__ values, const float* __restrict__ Wq,
    const float* __restrict__ Wk, const float* __restrict__ Wv,
    const float* __restrict__ Wo, short* __restrict__ u,
    float* __restrict__ dotb, float2* __restrict__ part,
    float* __restrict__ z, float* __restrict__ attn,
    float* __restrict__ out)
{
    cg::grid_group grid = cg::this_grid();
    __shared__ SharedU sh;
    int blk = blockIdx.x;
    int t = threadIdx.x;

    if (blk < 512) phase_u(blk, t, &sh, query, Wq, Wk, u);
    grid.sync();
    phase_dot(blk, t, &sh, keys, u, dotb, part);
    grid.sync();
    phase_z(blk, t, &sh, values, dotb, part, z);
    grid.sync();
    if (blk < 512) phase_attn(blk, t, &sh, z, Wv, attn);
    grid.sync();
    if (blk < 512) phase_out(blk, t, &sh, attn, Wo, out);
}

// ================= fallback wrappers (identical phase bodies) =================
__global__ __launch_bounds__(256, 4) void k_p1(const float* query, const float* Wq,
                                               const float* Wk, short* u) {
    __shared__ SharedU sh;
    phase_u(blockIdx.x, threadIdx.x, &sh, query, Wq, Wk, u);
}
__global__ __launch_bounds__(256, 4) void k_p2(const float* keys, const short* u,
                                               float* dotb, float2* part) {
    __shared__ SharedU sh;
    phase_dot(blockIdx.x, threadIdx.x, &sh, keys, u, dotb, part);
}
__global__ __launch_bounds__(256, 4) void k_p3(const float* values, const float* dotb,
                                               const float2* part, float* z) {
    __shared__ SharedU sh;
    phase_z(blockIdx.x, threadIdx.x, &sh, values, dotb, part, z);
}
__global__ __launch_bounds__(256, 4) void k_p4(const float* z, const float* Wv,
                                               float* attn) {
    __shared__ SharedU sh;
    phase_attn(blockIdx.x, threadIdx.x, &sh, z, Wv, attn);
}
__global__ __launch_bounds__(256, 4) void k_p5(const float* attn, const float* Wo,
                                               float* out) {
    __shared__ SharedU sh;
    phase_out(blockIdx.x, threadIdx.x, &sh, attn, Wo, out);
}

extern "C" void kernel_launch(void* const* d_in, const int* in_sizes, int n_in,
                              void* d_out, int out_size, void* d_ws, size_t ws_size,
                              hipStream_t stream) {
    const float* query  = (const float*)d_in[0];
    const float* keys   = (const float*)d_in[1];
    const float* values = (const float*)d_in[2];
    const float* Wq = (const float*)d_in[3];
    const float* Wk = (const float*)d_in[4];
    const float* Wv = (const float*)d_in[5];
    const float* Wo = (const float*)d_in[6];
    float* outp = (float*)d_out;

    char* ws = (char*)d_ws;
    short*  u    = (short*)(ws + 0);                          // 1 MB
    float*  dotb = (float*)(ws + (1 << 20));                  // 4 MB [b][s][h]
    float2* part = (float2*)(ws + (5 << 20));                 // 128 KB [b][32][16]
    float*  z    = (float*)(ws + (5 << 20) + (512 << 10));    // 4 MB (2 halves)
    float*  attn = (float*)(ws + (9 << 20) + (512 << 10));    // 128 KB

    void* args[13] = {
        (void*)&query, (void*)&keys, (void*)&values,
        (void*)&Wq, (void*)&Wk, (void*)&Wv, (void*)&Wo,
        (void*)&u, (void*)&dotb, (void*)&part, (void*)&z, (void*)&attn, (void*)&outp
    };
    hipError_t err = hipLaunchCooperativeKernel((const void*)k_mega, dim3(1024),
                                                dim3(256), args, 0, stream);
    if (err != hipSuccess) {
        // fallback: identical phase bodies as plain kernels
        hipLaunchKernelGGL(k_p1, dim3(512),  dim3(256), 0, stream, query, Wq, Wk, u);
        hipLaunchKernelGGL(k_p2, dim3(1024), dim3(256), 0, stream, keys, u, dotb, part);
        hipLaunchKernelGGL(k_p3, dim3(1024), dim3(256), 0, stream, values, dotb, part, z);
        hipLaunchKernelGGL(k_p4, dim3(512),  dim3(256), 0, stream, z, Wv, attn);
        hipLaunchKernelGGL(k_p5, dim3(512),  dim3(256), 0, stream, attn, Wo, outp);
    }
}

// Round 10
// 691.340 us; speedup vs baseline: 1.0175x; 1.0175x over previous
//
#include <hip/hip_runtime.h>
#include <hip/hip_cooperative_groups.h>

namespace cg = cooperative_groups;

#define SL  2048
#define BSZ 32
#define DIM 1024
#define NH  16
#define HD  64

typedef __attribute__((ext_vector_type(4))) float f32x4;
typedef __attribute__((ext_vector_type(2))) float f32x2;
typedef __attribute__((ext_vector_type(8))) short s16x8;

static __device__ __forceinline__ short f2bf(float f) {
    union { float f; unsigned u; } v; v.f = f;
    unsigned r = (v.u + 0x7fffu + ((v.u >> 16) & 1u)) >> 16;  // RNE
    return (short)r;
}

union SharedU {
    struct { float red[256]; float sq[HD]; } p1;
    union {
        short ulds[NH * 1024];                       // 32 KB, XOR-swizzled chunks
        struct { float mred[4][16]; float lred[4][16]; } r;  // time-aliased after MFMA
    } p2;
    struct { float wlds[128 * 16]; float Tl[16];
             float mred8[8][16]; float lred8[8][16];
             f32x2 redW[4][16][32]; } p3;            // 8K + 16K + ~1K = ~25.5 KB
    struct { float red[4][64]; } p45;
};
// sizeof(SharedU) == 32768 -> >=4 blocks/CU by LDS; launch_bounds(256,4) caps VGPR 128.

// ---------- phase 1: u[b][h][j] = 0.125 * sum_i (query[b].Wq[h*64+i]) * Wk[h*64+i][j]
static __device__ __forceinline__ void phase_u(int blk, int t, SharedU* sh,
                                               const float* __restrict__ query,
                                               const float* __restrict__ Wq,
                                               const float* __restrict__ Wk,
                                               short* __restrict__ u) {
    int b = blk & 31;
    int h = blk >> 5;
    {
        int i  = t >> 2;
        int kq = t & 3;
        const float* q = query + (size_t)b * DIM + kq * 256;
        const float* w = Wq + (size_t)(h * HD + i) * DIM + kq * 256;
        f32x4 acc = {0.f, 0.f, 0.f, 0.f};
#pragma unroll 4
        for (int k = 0; k < 256; k += 4)
            acc += *(const f32x4*)(q + k) * *(const f32x4*)(w + k);
        sh->p1.red[t] = acc[0] + acc[1] + acc[2] + acc[3];
    }
    __syncthreads();
    if (t < HD)
        sh->p1.sq[t] = (sh->p1.red[t*4] + sh->p1.red[t*4+1] +
                        sh->p1.red[t*4+2] + sh->p1.red[t*4+3]) * 0.125f;
    __syncthreads();
    f32x4 acc = {0.f, 0.f, 0.f, 0.f};
    const float* wk = Wk + (size_t)(h * HD) * DIM;
#pragma unroll 8
    for (int i = 0; i < HD; ++i) {
        float s = sh->p1.sq[i];
        const float* row = wk + (size_t)i * DIM;
        acc[0] += s * row[t];
        acc[1] += s * row[t + 256];
        acc[2] += s * row[t + 512];
        acc[3] += s * row[t + 768];
    }
    short* ub = u + ((size_t)(b * NH + h)) * DIM;
    ub[t]       = f2bf(acc[0]);
    ub[t + 256] = f2bf(acc[1]);
    ub[t + 512] = f2bf(acc[2]);
    ub[t + 768] = f2bf(acc[3]);
}

// ---------- phase 2: dot[b][s][h] + per-block LSE partials (1024 blocks: 32 b x 32 st)
static __device__ __forceinline__ void phase_dot(int blk, int t, SharedU* sh,
                                                 const float* __restrict__ keys,
                                                 const short* __restrict__ u,
                                                 float* __restrict__ dotb,
                                                 float2* __restrict__ part) {
    int b  = blk & 31;
    int st = blk >> 5;
    int s0 = st * 64;
    short* ulds = sh->p2.ulds;
    {   // stage u with 16B-chunk XOR swizzle: chunk c of row -> c ^ (row&7)
        const uint4* src = (const uint4*)(u + (size_t)b * NH * DIM);
        for (int idx = t; idx < NH * DIM / 8; idx += 256) {
            int row = idx >> 7;
            int c   = idx & 127;
            *(uint4*)&ulds[row * 1024 + ((c ^ (row & 7)) << 3)] = src[idx];
        }
    }
    __syncthreads();
    int lane = t & 63;
    int wave = t >> 6;
    int lrow = lane & 15;
    int kgrp = lane >> 4;
    int swz  = (lrow & 7) << 3;
    f32x4 acc = {0.f, 0.f, 0.f, 0.f};
    const float* ka = keys + ((size_t)(s0 + wave * 16 + lrow) * BSZ + b) * DIM;
#pragma unroll 4
    for (int k0 = 0; k0 < DIM; k0 += 32) {
        int kj = k0 + kgrp * 8;
        s16x8 bf = *(const s16x8*)&ulds[lrow * 1024 + (kj ^ swz)];
        f32x4 a0 = *(const f32x4*)(ka + kj);
        f32x4 a1 = *(const f32x4*)(ka + kj + 4);
        s16x8 af;
        af[0]=f2bf(a0[0]); af[1]=f2bf(a0[1]); af[2]=f2bf(a0[2]); af[3]=f2bf(a0[3]);
        af[4]=f2bf(a1[0]); af[5]=f2bf(a1[1]); af[6]=f2bf(a1[2]); af[7]=f2bf(a1[3]);
        acc = __builtin_amdgcn_mfma_f32_16x16x32_bf16(af, bf, acc, 0, 0, 0);
    }
    size_t obase = ((size_t)b * SL + (s0 + wave * 16 + kgrp * 4)) * NH + lrow;
#pragma unroll
    for (int r = 0; r < 4; ++r)
        dotb[obase + (size_t)r * NH] = acc[r];

    __syncthreads();   // ulds reads done -> alias with r.mred/r.lred
    float m = fmaxf(fmaxf(acc[0], acc[1]), fmaxf(acc[2], acc[3]));
    m = fmaxf(m, __shfl_xor(m, 16));
    m = fmaxf(m, __shfl_xor(m, 32));
    if (lane < 16) sh->p2.r.mred[wave][lrow] = m;
    __syncthreads();
    float mb = fmaxf(fmaxf(sh->p2.r.mred[0][lrow], sh->p2.r.mred[1][lrow]),
                     fmaxf(sh->p2.r.mred[2][lrow], sh->p2.r.mred[3][lrow]));
    float lsum = __expf(acc[0]-mb) + __expf(acc[1]-mb) + __expf(acc[2]-mb) + __expf(acc[3]-mb);
    lsum += __shfl_xor(lsum, 16);
    lsum += __shfl_xor(lsum, 32);
    if (lane < 16) sh->p2.r.lred[wave][lrow] = lsum;
    __syncthreads();
    if (t < 16) {
        float mbb = fmaxf(fmaxf(sh->p2.r.mred[0][t], sh->p2.r.mred[1][t]),
                          fmaxf(sh->p2.r.mred[2][t], sh->p2.r.mred[3][t]));
        float lb  = sh->p2.r.lred[0][t] + sh->p2.r.lred[1][t]
                  + sh->p2.r.lred[2][t] + sh->p2.r.lred[3][t];
        part[((size_t)b * 32 + st) * 16 + t] = make_float2(mbb, lb);
    }
}

// ---------- phase 3: z halves (1024 blocks: 32 b x 16 jc x 2 sh)
// LOW-PRESSURE FORM: 8 ssub x 32 jq, 2 j/thread -> acc[16] f32x2 = 32 VGPRs.
static __device__ __forceinline__ void phase_z(int blk, int t, SharedU* sh,
                                               const float* __restrict__ values,
                                               const float* __restrict__ dotb,
                                               const float2* __restrict__ part,
                                               float* __restrict__ z) {
    int b   = blk & 31;
    int jc  = (blk >> 5) & 15;
    int shf = blk >> 9;
    int ssub = t >> 5;               // 0..7
    int jq   = t & 31;               // 0..31
    int wv   = __builtin_amdgcn_readfirstlane(t >> 6);
    int lane = t & 63;

    if (t < 128) {
        int h = t & 15, g = t >> 4;
        const float2* pb = part + (size_t)b * 32 * 16 + h;
        float2 p0 = pb[(g*4+0)*16], p1 = pb[(g*4+1)*16],
               p2 = pb[(g*4+2)*16], p3v = pb[(g*4+3)*16];
        float M = fmaxf(fmaxf(p0.x, p1.x), fmaxf(p2.x, p3v.x));
        float L = p0.y*__expf(p0.x-M) + p1.y*__expf(p1.x-M)
                + p2.y*__expf(p2.x-M) + p3v.y*__expf(p3v.x-M);
        sh->p3.mred8[g][h] = M; sh->p3.lred8[g][h] = L;
    }
    __syncthreads();
    if (t < 16) {
        float M = sh->p3.mred8[0][t];
#pragma unroll
        for (int g = 1; g < 8; ++g) M = fmaxf(M, sh->p3.mred8[g][t]);
        float L = 0.f;
#pragma unroll
        for (int g = 0; g < 8; ++g) L += sh->p3.lred8[g][t] * __expf(sh->p3.mred8[g][t] - M);
        sh->p3.Tl[t] = M + __logf(L);
    }

    f32x2 acc[NH];
#pragma unroll
    for (int h = 0; h < NH; ++h) acc[h] = (f32x2){0.f, 0.f};
    f32x2 accV = {0.f, 0.f};

    const float* vbase = values + (size_t)b * DIM + jc * 64 + jq * 2;
    const float* wbase = dotb + ((size_t)b * SL + shf * 1024) * NH;

    for (int ph = 0; ph < 8; ++ph) {
        __syncthreads();
        {
            const f32x4* src = (const f32x4*)(wbase + ph * 128 * NH);
            f32x4* dst = (f32x4*)sh->p3.wlds;
            dst[t]       = src[t];
            dst[t + 256] = src[t + 256];
        }
        __syncthreads();
        int sbase = shf * 1024 + ph * 128;
#pragma unroll 4
        for (int it = 0; it < 16; ++it) {
            int s_loc = it * 8 + ssub;
            f32x2 v = *(const f32x2*)(vbase + (size_t)(sbase + s_loc) * (BSZ * DIM));
            const f32x4* wr = (const f32x4*)(sh->p3.wlds + s_loc * 16);
            f32x4 w0 = wr[0], w1 = wr[1], w2 = wr[2], w3 = wr[3];
            acc[0]  += v * w0[0];  acc[1]  += v * w0[1];
            acc[2]  += v * w0[2];  acc[3]  += v * w0[3];
            acc[4]  += v * w1[0];  acc[5]  += v * w1[1];
            acc[6]  += v * w1[2];  acc[7]  += v * w1[3];
            acc[8]  += v * w2[0];  acc[9]  += v * w2[1];
            acc[10] += v * w2[2];  acc[11] += v * w2[3];
            acc[12] += v * w3[0];  acc[13] += v * w3[1];
            acc[14] += v * w3[2];  acc[15] += v * w3[3];
            accV += v;
        }
    }

    // combine the wave's two ssub groups (lanes 32 apart), then LDS across waves
#pragma unroll
    for (int h = 0; h < NH; ++h) {
#pragma unroll
        for (int e = 0; e < 2; ++e) {
            float x0 = acc[h][e];
            x0 += __shfl_xor(x0, 32);
            acc[h][e] = x0;
        }
    }
#pragma unroll
    for (int e = 0; e < 2; ++e) {
        float x0 = accV[e];
        x0 += __shfl_xor(x0, 32);
        accV[e] = x0;
    }
    __syncthreads();                 // wlds no longer needed; redW region free
    if (lane < 32) {
#pragma unroll
        for (int h = 0; h < NH; ++h) sh->p3.redW[wv][h][lane] = acc[h];
    }
    __syncthreads();
    // final: 256 threads x 2 entries of (h, jq) over 16x32
    float Tsv[2];
    {
        // accV combine via redW pass 2 would alias; instead reduce accV through
        // mred8 region: [4][32] floats x2
        float* avx = (float*)sh->p3.mred8;     // reuse as [4][32][2]
        if (lane < 32) { avx[(wv * 32 + lane) * 2] = accV[0]; avx[(wv * 32 + lane) * 2 + 1] = accV[1]; }
    }
    __syncthreads();
    int h2 = t >> 4;                 // 0..15
    int q2 = (t & 15) * 2;           // 0,2,..,30
    const float* avx = (const float*)sh->p3.mred8;
#pragma unroll
    for (int e = 0; e < 2; ++e) {
        int q = q2 + e;              // jq 0..31
        f32x2 sumW = sh->p3.redW[0][h2][q] + sh->p3.redW[1][h2][q]
                   + sh->p3.redW[2][h2][q] + sh->p3.redW[3][h2][q];
        float sv0 = avx[(0 * 32 + q) * 2]     + avx[(1 * 32 + q) * 2]
                  + avx[(2 * 32 + q) * 2]     + avx[(3 * 32 + q) * 2];
        float sv1 = avx[(0 * 32 + q) * 2 + 1] + avx[(1 * 32 + q) * 2 + 1]
                  + avx[(2 * 32 + q) * 2 + 1] + avx[(3 * 32 + q) * 2 + 1];
        float Th = sh->p3.Tl[h2];
        float2 zv;
        zv.x = sumW[0] - Th * sv0;
        zv.y = sumW[1] - Th * sv1;
        float* zp = z + (size_t)shf * (BSZ * NH * DIM);
        *(float2*)(zp + ((size_t)(b * NH + h2)) * DIM + jc * 64 + q * 2) = zv;
    }
    (void)Tsv;
}

// ---------- phase 4: attn = (z0+z1) @ Wv^T  (512 blocks: 16 oc x 32 b)
static __device__ __forceinline__ void phase_attn(int blk, int t, SharedU* sh,
                                                  const float* __restrict__ z,
                                                  const float* __restrict__ Wv,
                                                  float* __restrict__ attn) {
    int oc = blk & 15;
    int b  = blk >> 4;
    int wv = __builtin_amdgcn_readfirstlane(t >> 6);
    int lane = t & 63;
    int o = oc * 64 + lane;
    int row = b * 16 + oc;
    const float* arow  = z + (size_t)row * DIM + wv * 256;
    const float* a2row = z + (size_t)(BSZ * NH * DIM) + (size_t)row * DIM + wv * 256;
    const float* wrow  = Wv + (size_t)o * DIM + wv * 256;
    f32x4 acc = {0.f, 0.f, 0.f, 0.f};
#pragma unroll 4
    for (int k = 0; k < 256; k += 4) {
        f32x4 a = *(const f32x4*)(arow + k) + *(const f32x4*)(a2row + k);
        acc += a * *(const f32x4*)(wrow + k);
    }
    sh->p45.red[wv][lane] = acc[0] + acc[1] + acc[2] + acc[3];
    __syncthreads();
    if (t < 64)
        attn[(size_t)b * DIM + oc * 64 + t] =
            sh->p45.red[0][t] + sh->p45.red[1][t] + sh->p45.red[2][t] + sh->p45.red[3][t];
}

// ---------- phase 5: out = attn @ Wo^T  (512 blocks)
static __device__ __forceinline__ void phase_out(int blk, int t, SharedU* sh,
                                                 const float* __restrict__ attn,
                                                 const float* __restrict__ Wo,
                                                 float* __restrict__ out) {
    int oc = blk & 15;
    int b  = blk >> 4;
    int wv = __builtin_amdgcn_readfirstlane(t >> 6);
    int lane = t & 63;
    int o = oc * 64 + lane;
    const float* arow = attn + (size_t)b * DIM + wv * 256;
    const float* wrow = Wo + (size_t)o * DIM + wv * 256;
    f32x4 acc = {0.f, 0.f, 0.f, 0.f};
#pragma unroll 4
    for (int k = 0; k < 256; k += 4)
        acc += *(const f32x4*)(arow + k) * *(const f32x4*)(wrow + k);
    sh->p45.red[wv][lane] = acc[0] + acc[1] + acc[2] + acc[3];
    __syncthreads();
    if (t < 64)
        out[(size_t)b * DIM + oc * 64 + t] =
            sh->p45.red[0][t] + sh->p45.red[1][t] + sh->p45.red[2][t] + sh->p45.red[3][t];
}

// ================= fused cooperative kernel =================
__global__ __launch_bounds__(256, 4) void k_mega(
    const float* __restrict__ query, const float* __restrict__ keys,
    const float* __restrict__ values, const float* __restrict__ Wq,
    const float* __restrict__ Wk, const float* __restrict__ Wv,
    const float* __restrict__ Wo, short* __restrict__ u,
    float* __restrict__ dotb, float2* __restrict__ part,
    float* __restrict__ z, float* __restrict__ attn,
    float* __restrict__ out)
{
    cg::grid_group grid = cg::this_grid();
    __shared__ SharedU sh;
    int blk = blockIdx.x;
    int t = threadIdx.x;

    if (blk < 512) phase_u(blk, t, &sh, query, Wq, Wk, u);
    grid.sync();
    phase_dot(blk, t, &sh, keys, u, dotb, part);
    grid.sync();
    phase_z(blk, t, &sh, values, dotb, part, z);
    grid.sync();
    if (blk < 512) phase_attn(blk, t, &sh, z, Wv, attn);
    grid.sync();
    if (blk < 512) phase_out(blk, t, &sh, attn, Wo, out);
}

// ================= fallback wrappers (identical phase bodies) =================
__global__ __launch_bounds__(256, 4) void k_p1(const float* query, const float* Wq,
                                               const float* Wk, short* u) {
    __shared__ SharedU sh;
    phase_u(blockIdx.x, threadIdx.x, &sh, query, Wq, Wk, u);
}
__global__ __launch_bounds__(256, 4) void k_p2(const float* keys, const short* u,
                                               float* dotb, float2* part) {
    __shared__ SharedU sh;
    phase_dot(blockIdx.x, threadIdx.x, &sh, keys, u, dotb, part);
}
__global__ __launch_bounds__(256, 4) void k_p3(const float* values, const float* dotb,
                                               const float2* part, float* z) {
    __shared__ SharedU sh;
    phase_z(blockIdx.x, threadIdx.x, &sh, values, dotb, part, z);
}
__global__ __launch_bounds__(256, 4) void k_p4(const float* z, const float* Wv,
                                               float* attn) {
    __shared__ SharedU sh;
    phase_attn(blockIdx.x, threadIdx.x, &sh, z, Wv, attn);
}
__global__ __launch_bounds__(256, 4) void k_p5(const float* attn, const float* Wo,
                                               float* out) {
    __shared__ SharedU sh;
    phase_out(blockIdx.x, threadIdx.x, &sh, attn, Wo, out);
}

extern "C" void kernel_launch(void* const* d_in, const int* in_sizes, int n_in,
                              void* d_out, int out_size, void* d_ws, size_t ws_size,
                              hipStream_t stream) {
    const float* query  = (const float*)d_in[0];
    const float* keys   = (const float*)d_in[1];
    const float* values = (const float*)d_in[2];
    const float* Wq = (const float*)d_in[3];
    const float* Wk = (const float*)d_in[4];
    const float* Wv = (const float*)d_in[5];
    const float* Wo = (const float*)d_in[6];
    float* outp = (float*)d_out;

    char* ws = (char*)d_ws;
    short*  u    = (short*)(ws + 0);                          // 1 MB
    float*  dotb = (float*)(ws + (1 << 20));                  // 4 MB [b][s][h]
    float2* part = (float2*)(ws + (5 << 20));                 // 128 KB [b][32][16]
    float*  z    = (float*)(ws + (5 << 20) + (512 << 10));    // 4 MB (2 halves)
    float*  attn = (float*)(ws + (9 << 20) + (512 << 10));    // 128 KB

    void* args[13] = {
        (void*)&query, (void*)&keys, (void*)&values,
        (void*)&Wq, (void*)&Wk, (void*)&Wv, (void*)&Wo,
        (void*)&u, (void*)&dotb, (void*)&part, (void*)&z, (void*)&attn, (void*)&outp
    };
    hipError_t err = hipLaunchCooperativeKernel((const void*)k_mega, dim3(1024),
                                                dim3(256), args, 0, stream);
    if (err != hipSuccess) {
        hipLaunchKernelGGL(k_p1, dim3(512),  dim3(256), 0, stream, query, Wq, Wk, u);
        hipLaunchKernelGGL(k_p2, dim3(1024), dim3(256), 0, stream, keys, u, dotb, part);
        hipLaunchKernelGGL(k_p3, dim3(1024), dim3(256), 0, stream, values, dotb, part, z);
        hipLaunchKernelGGL(k_p4, dim3(512),  dim3(256), 0, stream, z, Wv, attn);
        hipLaunchKernelGGL(k_p5, dim3(512),  dim3(256), 0, stream, attn, Wo, outp);
    }
}

// Round 11
// 227.383 us; speedup vs baseline: 3.0936x; 3.0404x over previous
//
#include <hip/hip_runtime.h>

#define SL  2048
#define BSZ 32
#define DIM 1024
#define NH  16
#define HD  64

typedef __attribute__((ext_vector_type(4))) float f32x4;
typedef __attribute__((ext_vector_type(2))) float f32x2;
typedef __attribute__((ext_vector_type(8))) short s16x8;

static __device__ __forceinline__ short f2bf(float f) {
    union { float f; unsigned u; } v; v.f = f;
    unsigned r = (v.u + 0x7fffu + ((v.u >> 16) & 1u)) >> 16;  // RNE
    return (short)r;
}

// Fused q-projection + u (R5 form): u[b][h][j] = 0.125*sum_i(query[b].Wq[h*64+i])*Wk[h*64+i][j]
__global__ __launch_bounds__(256) void k_qu(const float* __restrict__ query,
                                            const float* __restrict__ Wq,
                                            const float* __restrict__ Wk,
                                            short* __restrict__ u) {
    int b = blockIdx.x & 31;
    int h = blockIdx.x >> 5;
    int t = threadIdx.x;
    __shared__ float red[256];
    __shared__ float sq[HD];
    {
        int i  = t >> 2;
        int kq = t & 3;
        const float* q = query + (size_t)b * DIM + kq * 256;
        const float* w = Wq + (size_t)(h * HD + i) * DIM + kq * 256;
        f32x4 acc = {0.f, 0.f, 0.f, 0.f};
#pragma unroll 4
        for (int k = 0; k < 256; k += 4)
            acc += *(const f32x4*)(q + k) * *(const f32x4*)(w + k);
        red[t] = acc[0] + acc[1] + acc[2] + acc[3];
    }
    __syncthreads();
    if (t < HD) sq[t] = (red[t*4] + red[t*4+1] + red[t*4+2] + red[t*4+3]) * 0.125f;
    __syncthreads();
    f32x4 acc = {0.f, 0.f, 0.f, 0.f};
    const float* wk = Wk + (size_t)(h * HD) * DIM;
#pragma unroll 8
    for (int i = 0; i < HD; ++i) {
        float s = sq[i];
        const float* row = wk + (size_t)i * DIM;
        acc[0] += s * row[t];
        acc[1] += s * row[t + 256];
        acc[2] += s * row[t + 512];
        acc[3] += s * row[t + 768];
    }
    short* ub = u + ((size_t)(b * NH + h)) * DIM;
    ub[t]       = f2bf(acc[0]);
    ub[t + 256] = f2bf(acc[1]);
    ub[t + 512] = f2bf(acc[2]);
    ub[t + 768] = f2bf(acc[3]);
}

// dot[b][s][h] + LSE partials. 512 blocks (32 b x 16 st of 128 s) x 512 threads
// (8 waves x 16 rows). 24 waves/CU target (was 16).
__global__ __launch_bounds__(512, 6) void k_dot(const float* __restrict__ keys,
                                                const short* __restrict__ u,
                                                float* __restrict__ dot,
                                                float2* __restrict__ part) {
    int b  = blockIdx.x & 31;
    int st = blockIdx.x >> 5;          // 0..15
    int s0 = st * 128;
    __shared__ short ulds[NH][DIM + 8];
    __shared__ float mred[8][16], lred[8][16];
    int t = threadIdx.x;
    {
        const uint4* src = (const uint4*)(u + (size_t)b * NH * DIM);
#pragma unroll
        for (int r = 0; r < 4; ++r) {
            int idx = t + r * 512;
            int row = idx >> 7;
            int col = (idx & 127) * 8;
            *(uint4*)&ulds[row][col] = src[idx];
        }
    }
    __syncthreads();
    int lane = t & 63;
    int wave = t >> 6;                 // 0..7
    int lrow = lane & 15;              // = h (C-layout column)
    int kgrp = lane >> 4;
    f32x4 acc = {0.f, 0.f, 0.f, 0.f};
    const float* ka = keys + ((size_t)(s0 + wave * 16 + lrow) * BSZ + b) * DIM;
#pragma unroll 4
    for (int k0 = 0; k0 < DIM; k0 += 32) {
        int kj = k0 + kgrp * 8;
        s16x8 bf = *(const s16x8*)&ulds[lrow][kj];
        f32x4 a0 = *(const f32x4*)(ka + kj);
        f32x4 a1 = *(const f32x4*)(ka + kj + 4);
        s16x8 af;
        af[0]=f2bf(a0[0]); af[1]=f2bf(a0[1]); af[2]=f2bf(a0[2]); af[3]=f2bf(a0[3]);
        af[4]=f2bf(a1[0]); af[5]=f2bf(a1[1]); af[6]=f2bf(a1[2]); af[7]=f2bf(a1[3]);
        acc = __builtin_amdgcn_mfma_f32_16x16x32_bf16(af, bf, acc, 0, 0, 0);
    }
    size_t obase = ((size_t)b * SL + (s0 + wave * 16 + kgrp * 4)) * NH + lrow;
#pragma unroll
    for (int r = 0; r < 4; ++r)
        dot[obase + (size_t)r * NH] = acc[r];

    // LSE partial over this block's 128 s, per h=lrow
    float m = fmaxf(fmaxf(acc[0], acc[1]), fmaxf(acc[2], acc[3]));
    m = fmaxf(m, __shfl_xor(m, 16));
    m = fmaxf(m, __shfl_xor(m, 32));
    if (lane < 16) mred[wave][lrow] = m;
    __syncthreads();
    float mb = mred[0][lrow];
#pragma unroll
    for (int w = 1; w < 8; ++w) mb = fmaxf(mb, mred[w][lrow]);
    float l = __expf(acc[0]-mb) + __expf(acc[1]-mb) + __expf(acc[2]-mb) + __expf(acc[3]-mb);
    l += __shfl_xor(l, 16);
    l += __shfl_xor(l, 32);
    if (lane < 16) lred[wave][lrow] = l;
    __syncthreads();
    if (t < 16) {
        float mbb = mred[0][t];
#pragma unroll
        for (int w = 1; w < 8; ++w) mbb = fmaxf(mbb, mred[w][t]);
        float lb = lred[0][t];
#pragma unroll
        for (int w = 1; w < 8; ++w) lb += lred[w][t];
        part[((size_t)b * 16 + st) * 16 + t] = make_float2(mbb, lb);
    }
}

// z[b][h][j] = sum_s (dot-T)*v. 512 blocks (32 b x 16 jc of 64 j) x 512 threads
// (16 ssub x 32 jq, 2 j/thread -> acc 32 VGPR; 256B-contiguous values reads).
__global__ __launch_bounds__(512, 6) void k_z(const float* __restrict__ values,
                                              const float* __restrict__ dotb,
                                              const float2* __restrict__ part,
                                              float* __restrict__ z) {
    int b  = blockIdx.x & 31;
    int jc = blockIdx.x >> 5;          // 0..15
    int t  = threadIdx.x;
    int ssub = t >> 5;                 // 0..15
    int jq   = t & 31;                 // 0..31
    int wave = t >> 6;                 // 0..7
    int lane = t & 63;

    __shared__ float wlds[128 * 16];   // 8 KB
    __shared__ float Tl[16];
    __shared__ f32x2 redW[8][16][32];  // 32 KB
    __shared__ f32x2 redV[8][32];      // 2 KB

    if (t < 16) {
        const float2* pb = part + (size_t)b * 16 * 16 + t;
        float M = -1e30f;
#pragma unroll
        for (int i = 0; i < 16; ++i) M = fmaxf(M, pb[i * 16].x);
        float L = 0.f;
#pragma unroll
        for (int i = 0; i < 16; ++i) { float2 p = pb[i * 16]; L += p.y * __expf(p.x - M); }
        Tl[t] = M + __logf(L);
    }

    f32x2 acc[NH];
#pragma unroll
    for (int h = 0; h < NH; ++h) acc[h] = (f32x2){0.f, 0.f};
    f32x2 accV = {0.f, 0.f};

    const float* vbase = values + (size_t)b * DIM + jc * 64 + jq * 2;
    const float* wbase = dotb + (size_t)b * SL * NH;

    for (int ph = 0; ph < 16; ++ph) {
        __syncthreads();
        {   // stage dot[s0..s0+128][16] : 8 KB, one f32x4 per thread
            const f32x4* src = (const f32x4*)(wbase + ph * 128 * NH);
            ((f32x4*)wlds)[t] = src[t];
        }
        __syncthreads();
        int sbase = ph * 128;
#pragma unroll 4
        for (int it = 0; it < 8; ++it) {
            int s_loc = it * 16 + ssub;
            f32x2 v = *(const f32x2*)(vbase + (size_t)(sbase + s_loc) * (BSZ * DIM));
            const f32x4* wr = (const f32x4*)(wlds + s_loc * 16);
            f32x4 w0 = wr[0], w1 = wr[1], w2 = wr[2], w3 = wr[3];
            acc[0]  += v * w0[0];  acc[1]  += v * w0[1];
            acc[2]  += v * w0[2];  acc[3]  += v * w0[3];
            acc[4]  += v * w1[0];  acc[5]  += v * w1[1];
            acc[6]  += v * w1[2];  acc[7]  += v * w1[3];
            acc[8]  += v * w2[0];  acc[9]  += v * w2[1];
            acc[10] += v * w2[2];  acc[11] += v * w2[3];
            acc[12] += v * w3[0];  acc[13] += v * w3[1];
            acc[14] += v * w3[2];  acc[15] += v * w3[3];
            accV += v;
        }
    }

    // wave covers ssub {2w, 2w+1}: lanes 32 apart -> one shfl folds them
#pragma unroll
    for (int h = 0; h < NH; ++h) {
#pragma unroll
        for (int e = 0; e < 2; ++e) {
            float x0 = acc[h][e];
            x0 += __shfl_xor(x0, 32);
            acc[h][e] = x0;
        }
    }
#pragma unroll
    for (int e = 0; e < 2; ++e) {
        float x0 = accV[e];
        x0 += __shfl_xor(x0, 32);
        accV[e] = x0;
    }
    if (lane < 32) {
#pragma unroll
        for (int h = 0; h < NH; ++h) redW[wave][h][lane] = acc[h];
        redV[wave][lane] = accV;
    }
    __syncthreads();
    // final: 512 threads = 16 h x 32 jq
    {
        int h = t >> 5, q = t & 31;
        f32x2 sumW = redW[0][h][q];
        f32x2 sumV = redV[0][q];
#pragma unroll
        for (int w = 1; w < 8; ++w) { sumW += redW[w][h][q]; sumV += redV[w][q]; }
        float Th = Tl[h];
        float2 zv;
        zv.x = sumW[0] - Th * sumV[0];
        zv.y = sumW[1] - Th * sumV[1];
        *(float2*)(z + ((size_t)(b * NH + h)) * DIM + jc * 64 + q * 2) = zv;
    }
}

// O[b][o] = dot(A_row(b,o), W[o][:]) — R5 k_gemm form (512 blocks x 256 thr).
__global__ __launch_bounds__(256) void k_gemm(const float* __restrict__ A,
                                              const float* __restrict__ W,
                                              float* __restrict__ O,
                                              int rmul, int hsel) {
    int oc = blockIdx.x & 15;
    int b  = blockIdx.x >> 4;
    int wv = __builtin_amdgcn_readfirstlane(threadIdx.x >> 6);
    int lane = threadIdx.x & 63;
    int o = oc * 64 + lane;
    int row = b * rmul + (hsel ? oc : 0);
    const float* arow = A + (size_t)row * DIM + wv * 256;
    const float* wrow = W + (size_t)o * DIM + wv * 256;
    f32x4 acc = {0.f, 0.f, 0.f, 0.f};
#pragma unroll 4
    for (int k = 0; k < 256; k += 4) {
        f32x4 a = *(const f32x4*)(arow + k);
        f32x4 w = *(const f32x4*)(wrow + k);
        acc += a * w;
    }
    __shared__ float red[4][64];
    red[wv][lane] = acc[0] + acc[1] + acc[2] + acc[3];
    __syncthreads();
    int t = threadIdx.x;
    if (t < 64)
        O[(size_t)b * DIM + oc * 64 + t] = red[0][t] + red[1][t] + red[2][t] + red[3][t];
}

extern "C" void kernel_launch(void* const* d_in, const int* in_sizes, int n_in,
                              void* d_out, int out_size, void* d_ws, size_t ws_size,
                              hipStream_t stream) {
    const float* query  = (const float*)d_in[0];
    const float* keys   = (const float*)d_in[1];
    const float* values = (const float*)d_in[2];
    const float* Wq = (const float*)d_in[3];
    const float* Wk = (const float*)d_in[4];
    const float* Wv = (const float*)d_in[5];
    const float* Wo = (const float*)d_in[6];
    float* out = (float*)d_out;

    char* ws = (char*)d_ws;
    short*  u    = (short*)(ws + 0);                        // 1 MB
    float*  dotb = (float*)(ws + (1 << 20));                // 4 MB [b][s][h]
    float2* part = (float2*)(ws + (5 << 20));               // 64 KB [b][16][16]
    float*  z    = (float*)(ws + (5 << 20) + (128 << 10));  // 2 MB [b][h][j]
    float*  attn = (float*)(ws + (7 << 20) + (128 << 10));  // 128 KB

    hipLaunchKernelGGL(k_qu,   dim3(512), dim3(256), 0, stream, query, Wq, Wk, u);
    hipLaunchKernelGGL(k_dot,  dim3(512), dim3(512), 0, stream, keys, u, dotb, part);
    hipLaunchKernelGGL(k_z,    dim3(512), dim3(512), 0, stream, values, dotb, part, z);
    hipLaunchKernelGGL(k_gemm, dim3(512), dim3(256), 0, stream, z, Wv, attn, 16, 1);
    hipLaunchKernelGGL(k_gemm, dim3(512), dim3(256), 0, stream, attn, Wo, out, 1, 0);
}